// Round 18
// baseline (187.381 us; speedup 1.0000x reference)
//
#include <hip/hip_runtime.h>

// GraphConstruction: x[1,1024,1024] fp32 -> A[4096,4096] in {0,1} fp32.
// patches[n,r,k] = x[h,w], h = (n&15)*64 + (r>>2)*16 + (n>>8),
//                          w = (r&3)*256 + k*16 + ((n>>4)&15)
// LOCKED NUMERICS (R6..R17, absmax 0):
//   sq[n,k]: acc = p0^2; acc = acc + fl(p_r^2), r ascending (plain adds)
//   G: acc = fmaf(a_r, b_r, acc), r ascending
//   d2 = fmaf(-2,G,fl(si+sj));  all_k (d2 <= 49.0f);  A symmetric -> mirror.
// R18: R17 proved DS-read ISSUE is the binder (conflicts 0, dur flat at
//   ~111us = 2048 b128 x 12cyc x 8.1 blk/CU) and 2 reads/(r,k)/thread is the
//   4x4-tile information floor. Take the a-stream off the DS pipe: a-read =
//   4 distinct 16B in 64B = ONE L2 line per wave-instr from P2 (VMEM).
//   R16's failure mode (compiler hoists 64 loads -> VGPR 128) is capped
//   structurally: unroll 4 on the r-loop + launch_bounds(256,5) (cap 102).
//   Only j-tile staged (8KB LDS, coalesced from P2). fmaxf epilogue (R13-
//   proven). DS/block 2176 -> ~1100 instr; VALU (~36us) becomes the binder.

#define NPATCH 4096
#define BT 64

// ---- P2[k][r][n] transpose (verified R15/R16/R17) ----
__global__ __launch_bounds__(256) void transpose_kernel(const float* __restrict__ x,
                                                        float* __restrict__ P2) {
    int gid = blockIdx.x * 256 + threadIdx.x;   // 262144
    int nl = gid & 15;
    int c  = (gid >> 4) & 3;
    int n8 = (gid >> 6) & 15;
    int r  = (gid >> 10) & 15;
    int k  = gid >> 14;
    int h = nl * 64 + (r >> 2) * 16 + n8;
    int w0 = (r & 3) * 256 + k * 16 + 4 * c;
    float4 v = *(const float4*)&x[h * 1024 + w0];
    const float* vp = (const float*)&v;
    float* dst = P2 + (((k * 16 + r) << 12) | (n8 << 8) | nl);
#pragma unroll
    for (int j = 0; j < 4; ++j)
        dst[(4 * c + j) << 4] = vp[j];
}

// ---- sq[k][n] (verified R15/R16/R17) ----
__global__ __launch_bounds__(256) void sq2_kernel(const float* __restrict__ P2,
                                                  float* __restrict__ sq) {
#pragma clang fp contract(off)
    int gid = blockIdx.x * 256 + threadIdx.x;   // 65536
    int n = gid & 4095;
    int k = gid >> 12;
    const float* p = P2 + ((k * 16) << 12) + n;
    float v0 = p[0];
    float acc = v0 * v0;
#pragma unroll
    for (int r = 1; r < 16; ++r) {
        float v = p[r << 12];
        float t = v * v;
        acc = acc + t;
    }
    sq[(k << 12) + n] = acc;
}

// ---- adjacency: a-stream via VMEM (1 line/wave-instr), b-stream via LDS ----
__global__ __launch_bounds__(256, 5) void adj5_kernel(const float* __restrict__ P2,
                                                      const float* __restrict__ sq,
                                                      float* __restrict__ A) {
#pragma clang fp contract(off)
    __shared__ float4 Sj[2][16][16];   // [kl][r][chunk] = 8 KB

    // linear -> lower-triangle (bi >= bj)
    int t = blockIdx.x;
    int bi = (int)((sqrtf(8.0f * (float)t + 1.0f) - 1.0f) * 0.5f);
    while ((bi + 1) * (bi + 2) / 2 <= t) ++bi;
    while (bi * (bi + 1) / 2 > t) --bi;
    int bj = t - bi * (bi + 1) / 2;

    const int i0 = bi * BT;
    const int j0 = bj * BT;
    const int tid = threadIdx.x;
    const int tx = tid & 15;       // j-cols tx*4..+3
    const int ty = tid >> 4;       // i-rows ty*4..+3
    const int ia = i0 + 4 * ty;
    const int ja = j0 + 4 * tx;

    float m[4][4];
#pragma unroll
    for (int u = 0; u < 4; ++u)
#pragma unroll
        for (int v = 0; v < 4; ++v) m[u][v] = -3.0e38f;

    for (int kp = 0; kp < 8; ++kp) {
        __syncthreads();
        // ---- stage j-tile (2 k) from P2: coalesced loads, b128 writes ----
#pragma unroll
        for (int l = 0; l < 2; ++l) {
            int gid = l * 256 + tid;           // kl(1)|r(4)|c(4)
            int c = gid & 15;
            int r = (gid >> 4) & 15;
            int kl = gid >> 8;
            int k = kp * 2 + kl;
            Sj[kl][r][c] = *(const float4*)&P2[(((k << 4) | r) << 12) + j0 + 4 * c];
        }
        __syncthreads();
        // ---- compute: a from global (1 line/wave-instr), b from LDS ----
#pragma unroll
        for (int kl = 0; kl < 2; ++kl) {
            int k = kp * 2 + kl;
            const float* baseA = P2 + (((size_t)k << 4) << 12) + ia;
            float d[4][4];
#pragma unroll
            for (int u = 0; u < 4; ++u)
#pragma unroll
                for (int v = 0; v < 4; ++v) d[u][v] = 0.0f;
#pragma unroll 4
            for (int r = 0; r < 16; ++r) {
                float4 a4 = *(const float4*)&baseA[r << 12];
                float4 b4 = Sj[kl][r][tx];     // 16 distinct f4: 2-way, free
                const float* ap = (const float*)&a4;
                const float* bp = (const float*)&b4;
#pragma unroll
                for (int u = 0; u < 4; ++u)
#pragma unroll
                    for (int v = 0; v < 4; ++v)
                        d[u][v] = fmaf(ap[u], bp[v], d[u][v]);
            }
            float4 si4 = *(const float4*)&sq[(k << 12) + ia];
            float4 sj4 = *(const float4*)&sq[(k << 12) + ja];
            const float* sip = (const float*)&si4;
            const float* sjp = (const float*)&sj4;
#pragma unroll
            for (int u = 0; u < 4; ++u)
#pragma unroll
                for (int v = 0; v < 4; ++v) {
                    float s = sip[u] + sjp[v];            // fl(si+sj)
                    float d2 = fmaf(-2.0f, d[u][v], s);   // fl(s-2G)
                    m[u][v] = fmaxf(m[u][v], d2);
                }
        }
    }

    // ---- stores: direct + mirrored (A exactly symmetric) ----
#pragma unroll
    for (int u = 0; u < 4; ++u) {
        float4 o;
        o.x = (m[u][0] <= 49.0f) ? 1.0f : 0.0f;
        o.y = (m[u][1] <= 49.0f) ? 1.0f : 0.0f;
        o.z = (m[u][2] <= 49.0f) ? 1.0f : 0.0f;
        o.w = (m[u][3] <= 49.0f) ? 1.0f : 0.0f;
        *(float4*)&A[(size_t)(i0 + ty * 4 + u) * NPATCH + j0 + tx * 4] = o;
    }
    if (bi != bj) {
#pragma unroll
        for (int v = 0; v < 4; ++v) {
            float4 o;
            o.x = (m[0][v] <= 49.0f) ? 1.0f : 0.0f;
            o.y = (m[1][v] <= 49.0f) ? 1.0f : 0.0f;
            o.z = (m[2][v] <= 49.0f) ? 1.0f : 0.0f;
            o.w = (m[3][v] <= 49.0f) ? 1.0f : 0.0f;
            *(float4*)&A[(size_t)(j0 + tx * 4 + v) * NPATCH + i0 + ty * 4] = o;
        }
    }
}

// ====================== R13 fallback (proven, ws-free) ======================

#define KC 2
#define NPH 8
#define RSTRIDE 9

__device__ __forceinline__ int swzrow(int row) {
    return ((row >> 2) + (row >> 5)) & 7;
}

__global__ __launch_bounds__(256, 3) void adj_kernel(const float* __restrict__ x,
                                                     float* __restrict__ A) {
#pragma clang fp contract(off)
    __shared__ float4 Si[BT * RSTRIDE];
    __shared__ float4 Sj[BT * RSTRIDE];
    __shared__ float sqs[2][KC][BT];

    int t = blockIdx.x;
    int bi = (int)((sqrtf(8.0f * (float)t + 1.0f) - 1.0f) * 0.5f);
    while ((bi + 1) * (bi + 2) / 2 <= t) ++bi;
    while (bi * (bi + 1) / 2 > t) --bi;
    int bj = t - bi * (bi + 1) / 2;

    const int i0 = bi * BT;
    const int j0 = bj * BT;
    const int tid = threadIdx.x;
    const int tx = tid & 15;
    const int ty = tid >> 4;
    const int swzA = (ty + (ty >> 3)) & 7;
    const int swzB = (tx + (tx >> 3)) & 7;

    float m[4][4];
#pragma unroll
    for (int u = 0; u < 4; ++u)
#pragma unroll
        for (int v = 0; v < 4; ++v) m[u][v] = -3.0e38f;

    for (int kp = 0; kp < NPH; ++kp) {
        __syncthreads();
#pragma unroll
        for (int l = 0; l < 4; ++l) {
            int gid = l * 256 + tid;
            int side = gid >> 9;
            int q = gid & 511;
            int kl = q & 1;
            int r = (q >> 1) & 15;
            int rl = q >> 5;
            int k = kp * KC + kl;
            int b = side ? bj : bi;
            int h = rl * 64 + (r >> 2) * 16 + (b >> 2);
            int w0 = (r & 3) * 256 + k * 16 + ((4 * b) & 15);
            float4 v = *(const float4*)&x[h * 1024 + w0];
            const float* vp = (const float*)&v;
            int c = (kl << 2) | (r >> 2);
            int e = r & 3;
            float* Sb = side ? (float*)Sj : (float*)Si;
#pragma unroll
            for (int dd = 0; dd < 4; ++dd) {
                int row = 16 * dd + rl;
                int ch = c ^ swzrow(row);
                Sb[(row * RSTRIDE + ch) * 4 + e] = vp[dd];
            }
        }
        __syncthreads();
        {
            int side = tid >> 7;
            int kl = (tid >> 6) & 1;
            int row = tid & 63;
            const float4* Sb = (side ? Sj : Si) + row * RSTRIDE;
            int swz = swzrow(row);
            float acc;
            {
                float4 v = Sb[(kl * 4) ^ swz];
                acc = v.x * v.x;
                float t1 = v.y * v.y; acc = acc + t1;
                float t2 = v.z * v.z; acc = acc + t2;
                float t3 = v.w * v.w; acc = acc + t3;
            }
#pragma unroll
            for (int rc = 1; rc < 4; ++rc) {
                float4 v = Sb[(kl * 4 + rc) ^ swz];
                float t0 = v.x * v.x; acc = acc + t0;
                float t1 = v.y * v.y; acc = acc + t1;
                float t2 = v.z * v.z; acc = acc + t2;
                float t3 = v.w * v.w; acc = acc + t3;
            }
            sqs[side][kl][row] = acc;
        }
        __syncthreads();
#pragma unroll
        for (int kl = 0; kl < KC; ++kl) {
            float d[4][4];
#pragma unroll
            for (int u = 0; u < 4; ++u)
#pragma unroll
                for (int v = 0; v < 4; ++v) d[u][v] = 0.0f;
#pragma unroll
            for (int rc = 0; rc < 4; ++rc) {
                int c = kl * 4 + rc;
                float4 a[4], b[4];
#pragma unroll
                for (int u = 0; u < 4; ++u)
                    a[u] = Si[(ty * 4 + u) * RSTRIDE + (c ^ swzA)];
#pragma unroll
                for (int v = 0; v < 4; ++v)
                    b[v] = Sj[(tx * 4 + v) * RSTRIDE + (c ^ swzB)];
#pragma unroll
                for (int u = 0; u < 4; ++u)
#pragma unroll
                    for (int v = 0; v < 4; ++v) {
                        d[u][v] = fmaf(a[u].x, b[v].x, d[u][v]);
                        d[u][v] = fmaf(a[u].y, b[v].y, d[u][v]);
                        d[u][v] = fmaf(a[u].z, b[v].z, d[u][v]);
                        d[u][v] = fmaf(a[u].w, b[v].w, d[u][v]);
                    }
            }
            float4 si4 = *(const float4*)&sqs[0][kl][ty * 4];
            float4 sj4 = *(const float4*)&sqs[1][kl][tx * 4];
            const float* sip = (const float*)&si4;
            const float* sjp = (const float*)&sj4;
#pragma unroll
            for (int u = 0; u < 4; ++u)
#pragma unroll
                for (int v = 0; v < 4; ++v) {
                    float s = sip[u] + sjp[v];
                    float d2 = fmaf(-2.0f, d[u][v], s);
                    m[u][v] = fmaxf(m[u][v], d2);
                }
        }
    }

#pragma unroll
    for (int u = 0; u < 4; ++u) {
        float4 o;
        o.x = (m[u][0] <= 49.0f) ? 1.0f : 0.0f;
        o.y = (m[u][1] <= 49.0f) ? 1.0f : 0.0f;
        o.z = (m[u][2] <= 49.0f) ? 1.0f : 0.0f;
        o.w = (m[u][3] <= 49.0f) ? 1.0f : 0.0f;
        *(float4*)&A[(size_t)(i0 + ty * 4 + u) * NPATCH + j0 + tx * 4] = o;
    }
    if (bi != bj) {
#pragma unroll
        for (int v = 0; v < 4; ++v) {
            float4 o;
            o.x = (m[0][v] <= 49.0f) ? 1.0f : 0.0f;
            o.y = (m[1][v] <= 49.0f) ? 1.0f : 0.0f;
            o.z = (m[2][v] <= 49.0f) ? 1.0f : 0.0f;
            o.w = (m[3][v] <= 49.0f) ? 1.0f : 0.0f;
            *(float4*)&A[(size_t)(j0 + tx * 4 + v) * NPATCH + i0 + ty * 4] = o;
        }
    }
}

extern "C" void kernel_launch(void* const* d_in, const int* in_sizes, int n_in,
                              void* d_out, int out_size, void* d_ws, size_t ws_size,
                              hipStream_t stream) {
    const float* x = (const float*)d_in[0];
    float* A = (float*)d_out;

    const int nblk = (NPATCH / BT) * (NPATCH / BT + 1) / 2;  // 2080
    const size_t need = (size_t)4 * 1024 * 1024 + 256 * 1024;

    if (ws_size >= need) {
        float* P2 = (float*)d_ws;                                    // 4 MB
        float* sq = (float*)((char*)d_ws + (size_t)4 * 1024 * 1024); // 256 KB
        transpose_kernel<<<1024, 256, 0, stream>>>(x, P2);
        sq2_kernel<<<256, 256, 0, stream>>>(P2, sq);
        adj5_kernel<<<nblk, 256, 0, stream>>>(P2, sq, A);
    } else {
        adj_kernel<<<nblk, 256, 0, stream>>>(x, A);
    }
}